// Round 3
// baseline (99.081 us; speedup 1.0000x reference)
//
#include <hip/hip_runtime.h>

#define BB 16
#define HH 512
#define WW 512
// C = 3 floats per pixel

typedef float vf2 __attribute__((ext_vector_type(2)));
typedef float vf4 __attribute__((ext_vector_type(4)));

__device__ __forceinline__ void bilerp3(const float* __restrict__ img,
                                        int b, int y, int x,
                                        float dy, float dx,
                                        float* o0, float* o1, float* o2)
{
    const float qy = (float)y - dy;
    const float qx = (float)x - dx;

    const float y0f = fminf(fmaxf(floorf(qy), 0.0f), (float)(HH - 2));
    const float x0f = fminf(fmaxf(floorf(qx), 0.0f), (float)(WW - 2));
    const float ay = fminf(fmaxf(qy - y0f, 0.0f), 1.0f);
    const float ax = fminf(fmaxf(qx - x0f, 0.0f), 1.0f);
    const int y0 = (int)y0f;
    const int x0 = (int)x0f;

    const float* rowt = img + ((size_t)((b * HH + y0) * WW + x0)) * 3;
    const float* rowb = rowt + WW * 3;

    const float3 tl = *reinterpret_cast<const float3*>(rowt);
    const float3 tr = *reinterpret_cast<const float3*>(rowt + 3);
    const float3 bl = *reinterpret_cast<const float3*>(rowb);
    const float3 br = *reinterpret_cast<const float3*>(rowb + 3);

    const float t0 = fmaf(ax, tr.x - tl.x, tl.x);
    const float t1 = fmaf(ax, tr.y - tl.y, tl.y);
    const float t2 = fmaf(ax, tr.z - tl.z, tl.z);
    const float b0 = fmaf(ax, br.x - bl.x, bl.x);
    const float b1 = fmaf(ax, br.y - bl.y, bl.y);
    const float b2 = fmaf(ax, br.z - bl.z, bl.z);

    *o0 = fmaf(ay, b0 - t0, t0);
    *o1 = fmaf(ay, b1 - t1, t1);
    *o2 = fmaf(ay, b2 - t2, t2);
}

__global__ __launch_bounds__(256) void warp2_kernel(
    const float* __restrict__ frame0,
    const float* __restrict__ frame1,
    const float* __restrict__ f01,
    const float* __restrict__ f10,
    float* __restrict__ out)
{
    const int Npair    = BB * HH * WW;     // pairs across BOTH outputs
    const int halfPair = Npair >> 1;       // pairs per output
    const int stride   = gridDim.x * blockDim.x;

    for (int i = blockIdx.x * blockDim.x + threadIdx.x; i < Npair; i += stride) {
        const int which = i >= halfPair;
        const int pp = i - (which ? halfPair : 0);
        const float* __restrict__ img  = which ? frame1 : frame0;
        const float* __restrict__ flow = which ? f01    : f10;

        const int p0  = pp << 1;            // first pixel of the pair
        const int b   = p0 >> 18;           // / (512*512)
        const int rem = p0 & 262143;
        const int y   = rem >> 9;
        const int x   = rem & 511;          // even

        // flow for both pixels: [dy0, dx0, dy1, dx1], 16B-aligned
        const vf4 fl = __builtin_nontemporal_load(
            reinterpret_cast<const vf4*>(flow + 4 * (size_t)pp));

        float a0, a1, a2, c0, c1, c2;
        bilerp3(img, b, y, x,     fl.x, fl.y, &a0, &a1, &a2);
        bilerp3(img, b, y, x + 1, fl.z, fl.w, &c0, &c1, &c2);

        // 6 contiguous floats at out + 6*i (8B-aligned), nontemporal
        float* o = out + 6 * (size_t)i;
        vf2 v0 = {a0, a1};
        vf2 v1 = {a2, c0};
        vf2 v2 = {c1, c2};
        __builtin_nontemporal_store(v0, reinterpret_cast<vf2*>(o));
        __builtin_nontemporal_store(v1, reinterpret_cast<vf2*>(o + 2));
        __builtin_nontemporal_store(v2, reinterpret_cast<vf2*>(o + 4));
    }
}

extern "C" void kernel_launch(void* const* d_in, const int* in_sizes, int n_in,
                              void* d_out, int out_size, void* d_ws, size_t ws_size,
                              hipStream_t stream) {
    const float* frame0 = (const float*)d_in[0];
    const float* frame1 = (const float*)d_in[1];
    const float* f01    = (const float*)d_in[2];
    const float* f10    = (const float*)d_in[3];
    float* out = (float*)d_out;

    const int blocks = 4096;
    warp2_kernel<<<blocks, 256, 0, stream>>>(frame0, frame1, f01, f10, out);
}

// Round 4
// 77.503 us; speedup vs baseline: 1.2784x; 1.2784x over previous
//
#include <hip/hip_runtime.h>

#define BB 16
#define HH 512
#define WW 512
// C = 3 floats per pixel

typedef float vf4 __attribute__((ext_vector_type(4)));

__device__ __forceinline__ void bilerp3(const float* __restrict__ img,
                                        int b, int y, int x,
                                        float dy, float dx,
                                        float* o0, float* o1, float* o2)
{
    const float qy = (float)y - dy;
    const float qx = (float)x - dx;

    const float y0f = fminf(fmaxf(floorf(qy), 0.0f), (float)(HH - 2));
    const float x0f = fminf(fmaxf(floorf(qx), 0.0f), (float)(WW - 2));
    const float ay = fminf(fmaxf(qy - y0f, 0.0f), 1.0f);
    const float ax = fminf(fmaxf(qx - x0f, 0.0f), 1.0f);
    const int y0 = (int)y0f;
    const int x0 = (int)x0f;

    const float* rowt = img + ((size_t)((b * HH + y0) * WW + x0)) * 3;
    const float* rowb = rowt + WW * 3;

    const float3 tl = *reinterpret_cast<const float3*>(rowt);
    const float3 tr = *reinterpret_cast<const float3*>(rowt + 3);
    const float3 bl = *reinterpret_cast<const float3*>(rowb);
    const float3 br = *reinterpret_cast<const float3*>(rowb + 3);

    const float t0 = fmaf(ax, tr.x - tl.x, tl.x);
    const float t1 = fmaf(ax, tr.y - tl.y, tl.y);
    const float t2 = fmaf(ax, tr.z - tl.z, tl.z);
    const float b0 = fmaf(ax, br.x - bl.x, bl.x);
    const float b1 = fmaf(ax, br.y - bl.y, bl.y);
    const float b2 = fmaf(ax, br.z - bl.z, bl.z);

    *o0 = fmaf(ay, b0 - t0, t0);
    *o1 = fmaf(ay, b1 - t1, t1);
    *o2 = fmaf(ay, b2 - t2, t2);
}

// One block = one output row (512 px, 256 threads x 2 px).
// Total rows = 2 outputs * 16 batch * 512 = 16384 blocks.
// Bijective XCD-chunked swizzle: xcd = bid & 7 gets rows [xcd*2048, (xcd+1)*2048)
// in order -> image rows stay resident in that XCD's L2 across the ~6
// consecutive output rows that gather them.
__global__ __launch_bounds__(256) void warp2_kernel(
    const float* __restrict__ frame0,
    const float* __restrict__ frame1,
    const float* __restrict__ f01,
    const float* __restrict__ f10,
    float* __restrict__ out)
{
    const int bid = blockIdx.x;                 // 0..16383
    const int row_global = (bid & 7) * 2048 + (bid >> 3);   // bijective, 16384 = 8*2048

    const int which = row_global >= (BB * HH);  // 8192 rows per output
    const int r = row_global & (BB * HH - 1);   // row within its output
    const int b = r >> 9;                       // batch
    const int y = r & 511;

    const float* __restrict__ img  = which ? frame1 : frame0;
    const float* __restrict__ flow = which ? f01    : f10;

    const int t = threadIdx.x;                  // 0..255, covers x = 2t, 2t+1
    const int x = t << 1;

    // pair index within this output's flow: (b*512 + y)*256 + t
    const size_t pp = ((size_t)((b << 9) + y) << 8) + t;
    const vf4 fl = __builtin_nontemporal_load(
        reinterpret_cast<const vf4*>(flow + 4 * pp));

    float a0, a1, a2, c0, c1, c2;
    bilerp3(img, b, y, x,     fl.x, fl.y, &a0, &a1, &a2);
    bilerp3(img, b, y, x + 1, fl.z, fl.w, &c0, &c1, &c2);

    // concatenated pair index = row_global*256 + t; 6 floats per pair
    float* o = out + 6 * (((size_t)row_global << 8) + t);
    *reinterpret_cast<float3*>(o)     = make_float3(a0, a1, a2);
    *reinterpret_cast<float3*>(o + 3) = make_float3(c0, c1, c2);
}

extern "C" void kernel_launch(void* const* d_in, const int* in_sizes, int n_in,
                              void* d_out, int out_size, void* d_ws, size_t ws_size,
                              hipStream_t stream) {
    const float* frame0 = (const float*)d_in[0];
    const float* frame1 = (const float*)d_in[1];
    const float* f01    = (const float*)d_in[2];
    const float* f10    = (const float*)d_in[3];
    float* out = (float*)d_out;

    warp2_kernel<<<16384, 256, 0, stream>>>(frame0, frame1, f01, f10, out);
}